// Round 1
// baseline (155.445 us; speedup 1.0000x reference)
//
#include <hip/hip_runtime.h>

// SparseDopplerAttention on gfx950.
// 1 block = 1 range (256 blocks, 1/CU). 512 threads = 8 waves (2/SIMD).
// Phase A: project Q,K,V with mfma_f32_16x16x32_bf16 from LDS-staged x.
// Phase B: barrier-free flash attention per wave (64 queries), S^T orientation.

#define NK 512       // keys/queries per range
#define DOP 64
#define FIN 96
#define XS 104       // xb row stride (elements), 208 B = 13*16 -> aligned, 2-way banks
#define QS 72        // Qscr row stride (elements), 144 B = 9*16

typedef __bf16 bf16;
typedef bf16 v4bf __attribute__((ext_vector_type(4)));
typedef bf16 v8bf __attribute__((ext_vector_type(8)));
typedef float v4f __attribute__((ext_vector_type(4)));

__device__ __forceinline__ v4bf cvt4(float4 v) {
    v4bf b; b[0] = (bf16)v.x; b[1] = (bf16)v.y; b[2] = (bf16)v.z; b[3] = (bf16)v.w;
    return b;
}

__global__ __launch_bounds__(512, 2)
void sda_kernel(const float* __restrict__ power,
                const int*   __restrict__ ele_i,
                const int*   __restrict__ azi_i,
                const float* __restrict__ ele_t,
                const float* __restrict__ azi_t,
                const float* __restrict__ Wq, const float* __restrict__ bq,
                const float* __restrict__ Wk, const float* __restrict__ bk,
                const float* __restrict__ Wv, const float* __restrict__ bv,
                float* __restrict__ out)
{
    extern __shared__ char smem[];
    char* Kb  = smem;            // 65536 B: K [key][dim] bf16, row 128 B, dim-block ^= key&7
    char* Vt  = smem + 65536;    // 65536 B: V^T [dim][key] bf16, row 1024 B, key-block ^= dim&7
    char* Reg = smem + 131072;   // 32768 B: phase A: xb+Qscr; phase B: P scratch (4 KB/wave)
    bf16* xb   = (bf16*)Reg;                   // [64][XS]
    bf16* Qscr = (bf16*)(Reg + 64 * XS * 2);   // [64][QS]

    const int tid   = threadIdx.x;
    const int wave  = tid >> 6;
    const int lane  = tid & 63;
    const int l15   = lane & 15;
    const int quad  = lane >> 4;
    const int range = blockIdx.x;
    const int grow0 = range * NK;

    // ---- per-wave W fragments (K for waves 0-3, V for waves 4-7), biases ----
    const float* Wm = (wave < 4) ? Wk : Wv;
    const float* bm = (wave < 4) ? bk : bv;
    v8bf wf[4][3];
#pragma unroll
    for (int nt = 0; nt < 4; nt++)
#pragma unroll
        for (int kt = 0; kt < 3; kt++) {
            const float* p = Wm + (nt * 16 + l15) * FIN + kt * 32 + quad * 8;
            v8bf r;
#pragma unroll
            for (int j = 0; j < 8; j++) r[j] = (bf16)p[j];
            wf[nt][kt] = r;
        }
    float bm4[4], bq4[4];
#pragma unroll
    for (int nt = 0; nt < 4; nt++) {
        bm4[nt] = bm[nt * 16 + l15];
        bq4[nt] = bq[nt * 16 + l15];
    }

    v8bf qf[4][2];   // Q B-fragments, filled once (chunk == wave)

    // ================= Phase A: build K, V (LDS) and Q (regs) =================
    for (int c = 0; c < 8; c++) {
        __syncthreads();   // protect xb/Qscr reuse from previous chunk
        {
            // stage 64 rows of x as bf16: power (coalesced float4) + embeddings
            int colp = (tid & 15) * 4;
            int rowp = tid >> 4;
#pragma unroll
            for (int p = 0; p < 2; p++) {
                int row = rowp + p * 32;
                float4 v = *(const float4*)(power + (size_t)(grow0 + c * 64 + row) * DOP + colp);
                *(v4bf*)(xb + row * XS + colp) = cvt4(v);
            }
            int row = tid >> 3, sub = tid & 7;
            int gr = grow0 + c * 64 + row;
            if (sub < 4) {
                int idx = ele_i[gr];
                float4 v = *(const float4*)(ele_t + idx * 16 + sub * 4);
                *(v4bf*)(xb + row * XS + 64 + sub * 4) = cvt4(v);
            } else {
                int idx = azi_i[gr];
                float4 v = *(const float4*)(azi_t + idx * 16 + (sub - 4) * 4);
                *(v4bf*)(xb + row * XS + 80 + (sub - 4) * 4) = cvt4(v);
            }
        }
        __syncthreads();

        // ---- K (waves 0-3) / V (waves 4-7): one 16-row slice per wave ----
        {
            int slice = wave & 3;
            v8bf xa[3];
#pragma unroll
            for (int kt = 0; kt < 3; kt++)
                xa[kt] = *(const v8bf*)(xb + (slice * 16 + l15) * XS + kt * 32 + quad * 8);
#pragma unroll
            for (int nt = 0; nt < 4; nt++) {
                v4f acc = {0.f, 0.f, 0.f, 0.f};
#pragma unroll
                for (int kt = 0; kt < 3; kt++)
                    acc = __builtin_amdgcn_mfma_f32_16x16x32_bf16(xa[kt], wf[nt][kt], acc, 0, 0, 0);
                int d = nt * 16 + l15;
#pragma unroll
                for (int r = 0; r < 4; r++) {
                    int key = c * 64 + slice * 16 + quad * 4 + r;
                    bf16 val = (bf16)(acc[r] + bm4[nt]);
                    if (wave < 4)
                        *(bf16*)(Kb + key * 128 + ((((d >> 3) ^ (key & 7)) << 4) | ((d & 7) << 1))) = val;
                    else
                        *(bf16*)(Vt + d * 1024 + ((((key >> 3) ^ (d & 7)) << 4) | ((key & 7) << 1))) = val;
                }
            }
        }

        // ---- Q for the owning wave (its 64 queries == chunk c's rows) ----
        if (wave == c) {
            v8bf wqf[4][3];
#pragma unroll
            for (int nt = 0; nt < 4; nt++)
#pragma unroll
                for (int kt = 0; kt < 3; kt++) {
                    const float* p = Wq + (nt * 16 + l15) * FIN + kt * 32 + quad * 8;
                    v8bf r;
#pragma unroll
                    for (int j = 0; j < 8; j++) r[j] = (bf16)p[j];
                    wqf[nt][kt] = r;
                }
#pragma unroll
            for (int mt = 0; mt < 4; mt++) {
                v8bf qa[3];
#pragma unroll
                for (int kt = 0; kt < 3; kt++)
                    qa[kt] = *(const v8bf*)(xb + (mt * 16 + l15) * XS + kt * 32 + quad * 8);
#pragma unroll
                for (int nt = 0; nt < 4; nt++) {
                    v4f acc = {0.f, 0.f, 0.f, 0.f};
#pragma unroll
                    for (int kt = 0; kt < 3; kt++)
                        acc = __builtin_amdgcn_mfma_f32_16x16x32_bf16(qa[kt], wqf[nt][kt], acc, 0, 0, 0);
#pragma unroll
                    for (int r = 0; r < 4; r++) {
                        int row = mt * 16 + quad * 4 + r;
                        // fold 1/sqrt(64) and log2(e) into Q
                        Qscr[row * QS + nt * 16 + l15] =
                            (bf16)((acc[r] + bq4[nt]) * 0.18033688011112042f);
                    }
                }
            }
            // read back as B-operand fragments (query = lane&15 + nt*16)
#pragma unroll
            for (int nt = 0; nt < 4; nt++)
#pragma unroll
                for (int kt = 0; kt < 2; kt++)
                    qf[nt][kt] = *(const v8bf*)(Qscr + (nt * 16 + l15) * QS + kt * 32 + quad * 8);
        }
    }
    __syncthreads();   // K/V complete; Reg region becomes P scratch

    // ================= Phase B: flash attention, S^T orientation =================
    char* Pw = Reg + wave * 4096;   // per-wave P^T scratch [query][32 keys], swizzled
    v4f O[4][4];                    // O^T: row=dim (quad*4+r + mtd*16), col=query (l15 + nt*16)
#pragma unroll
    for (int a = 0; a < 4; a++)
#pragma unroll
        for (int b = 0; b < 4; b++) O[a][b] = (v4f){0.f, 0.f, 0.f, 0.f};
    float m_[4], l_[4];
#pragma unroll
    for (int nt = 0; nt < 4; nt++) { m_[nt] = -3.0e38f; l_[nt] = 0.f; }

    for (int t = 0; t < 16; t++) {
        // K A-fragments: key = t*32 + mtk*16 + l15, dims = kt*32 + quad*8 + j
        v8bf kf[2][2];
#pragma unroll
        for (int mtk = 0; mtk < 2; mtk++)
#pragma unroll
            for (int kt = 0; kt < 2; kt++) {
                int key = t * 32 + mtk * 16 + l15;
                kf[mtk][kt] = *(const v8bf*)(Kb + key * 128 + (((quad + kt * 4) ^ (key & 7)) << 4));
            }
        // S^T = K @ Q^T  (row=key, col=query), already in log2 domain
        v4f s[2][4];
#pragma unroll
        for (int mtk = 0; mtk < 2; mtk++)
#pragma unroll
            for (int nt = 0; nt < 4; nt++) {
                v4f acc = {0.f, 0.f, 0.f, 0.f};
                acc = __builtin_amdgcn_mfma_f32_16x16x32_bf16(kf[mtk][0], qf[nt][0], acc, 0, 0, 0);
                acc = __builtin_amdgcn_mfma_f32_16x16x32_bf16(kf[mtk][1], qf[nt][1], acc, 0, 0, 0);
                s[mtk][nt] = acc;
            }
        // online softmax over keys (rows of S^T): reduce regs, then quads (xor 16, 32)
        float alpha[4];
#pragma unroll
        for (int nt = 0; nt < 4; nt++) {
            float mx = fmaxf(fmaxf(fmaxf(s[0][nt][0], s[0][nt][1]), fmaxf(s[0][nt][2], s[0][nt][3])),
                             fmaxf(fmaxf(s[1][nt][0], s[1][nt][1]), fmaxf(s[1][nt][2], s[1][nt][3])));
            mx = fmaxf(mx, __shfl_xor(mx, 16));
            mx = fmaxf(mx, __shfl_xor(mx, 32));
            float nm = fmaxf(m_[nt], mx);
            alpha[nt] = __builtin_amdgcn_exp2f(m_[nt] - nm);
            m_[nt] = nm;
            float sum = 0.f;
#pragma unroll
            for (int mtk = 0; mtk < 2; mtk++)
#pragma unroll
                for (int r = 0; r < 4; r++) {
                    float p = __builtin_amdgcn_exp2f(s[mtk][nt][r] - nm);
                    s[mtk][nt][r] = p;
                    sum += p;
                }
            sum += __shfl_xor(sum, 16);
            sum += __shfl_xor(sum, 32);
            l_[nt] = l_[nt] * alpha[nt] + sum;
        }
        // rescale O^T
#pragma unroll
        for (int mtd = 0; mtd < 4; mtd++)
#pragma unroll
            for (int nt = 0; nt < 4; nt++) O[mtd][nt] *= alpha[nt];
        // write P^T to scratch: [query][key_local], key-block ^= query&3 (b64 writes)
#pragma unroll
        for (int mtk = 0; mtk < 2; mtk++)
#pragma unroll
            for (int nt = 0; nt < 4; nt++) {
                int q = nt * 16 + l15;
                v4bf pb;
                pb[0] = (bf16)s[mtk][nt][0]; pb[1] = (bf16)s[mtk][nt][1];
                pb[2] = (bf16)s[mtk][nt][2]; pb[3] = (bf16)s[mtk][nt][3];
                int blk = (mtk * 2 + (quad >> 1)) ^ (q & 3);
                *(v4bf*)(Pw + q * 64 + (blk << 4) + ((quad & 1) << 3)) = pb;
            }
        // O^T += V^T @ P^T : A = V^T frags, B = P^T frags (b128 reads)
        v8bf vf[4], pf[4];
#pragma unroll
        for (int mtd = 0; mtd < 4; mtd++) {
            int d = mtd * 16 + l15;
            vf[mtd] = *(const v8bf*)(Vt + d * 1024 + (((t * 4 + quad) ^ (d & 7)) << 4));
        }
#pragma unroll
        for (int nt = 0; nt < 4; nt++) {
            int q = nt * 16 + l15;
            pf[nt] = *(const v8bf*)(Pw + q * 64 + ((quad ^ (q & 3)) << 4));
        }
#pragma unroll
        for (int mtd = 0; mtd < 4; mtd++)
#pragma unroll
            for (int nt = 0; nt < 4; nt++)
                O[mtd][nt] = __builtin_amdgcn_mfma_f32_16x16x32_bf16(vf[mtd], pf[nt], O[mtd][nt], 0, 0, 0);
    }

    // ---- epilogue: out[q] = (sum_d O^T[d][q]) / l[q] ----
#pragma unroll
    for (int nt = 0; nt < 4; nt++) {
        float sm = 0.f;
#pragma unroll
        for (int mtd = 0; mtd < 4; mtd++)
#pragma unroll
            for (int r = 0; r < 4; r++) sm += O[mtd][nt][r];
        sm += __shfl_xor(sm, 16);
        sm += __shfl_xor(sm, 32);
        if (quad == 0) out[grow0 + wave * 64 + nt * 16 + l15] = sm / l_[nt];
    }
}

extern "C" void kernel_launch(void* const* d_in, const int* in_sizes, int n_in,
                              void* d_out, int out_size, void* d_ws, size_t ws_size,
                              hipStream_t stream) {
    const float* power = (const float*)d_in[0];
    const int*   ele_i = (const int*)d_in[1];
    // d_in[2] = range_indices: unused by the reference (positional reshape)
    const int*   azi_i = (const int*)d_in[3];
    const float* ele_t = (const float*)d_in[4];
    const float* azi_t = (const float*)d_in[5];
    const float* Wq = (const float*)d_in[6];
    const float* bq = (const float*)d_in[7];
    const float* Wk = (const float*)d_in[8];
    const float* bk = (const float*)d_in[9];
    const float* Wv = (const float*)d_in[10];
    const float* bv = (const float*)d_in[11];
    float* out = (float*)d_out;

    (void)hipFuncSetAttribute(reinterpret_cast<const void*>(sda_kernel),
                              hipFuncAttributeMaxDynamicSharedMemorySize, 163840);
    sda_kernel<<<256, 512, 163840, stream>>>(power, ele_i, azi_i, ele_t, azi_t,
                                             Wq, bq, Wk, bk, Wv, bv, out);
}